// Round 5
// baseline (372.908 us; speedup 1.0000x reference)
//
#include <hip/hip_runtime.h>

typedef short bf16x8 __attribute__((ext_vector_type(8)));
typedef float f32x4 __attribute__((ext_vector_type(4)));

__device__ __forceinline__ unsigned short f2bf(float f) {
  unsigned x = __float_as_uint(f);
  return (unsigned short)((x + 0x7fffu + ((x >> 16) & 1u)) >> 16);  // RNE
}
__device__ __forceinline__ unsigned b32pair(float a, float b) {
  return (unsigned)f2bf(a) | ((unsigned)f2bf(b) << 16);
}

// ---------------------------------------------------------------------------
// GEMM: BM=128, BN=256, BK=64. 512 thr = 8 waves (2m x 4n), 64x64 per wave.
// W fp32 streamed straight from HBM in 1 KB-contiguous rows (256 cols),
// masked per-column during staging, bf16-converted into XOR-swizzled LDS:
//   Ws[cc*64 + (k ^ (((cc^(cc>>3))&7)<<3))]     (write 4-way, read ~2-way)
//   Xs[ml*64 + (k ^ ((ml&7)<<3))]
// A: MODE1 reads x fp32 (L2-resident) + converts; MODE2 reads Hs, a bf16
// image pre-swizzled by reduce1 so staging is a verbatim linear copy.
// Split-K chunks of 8 iters; each chunk writes a private 128 KB slot in
// MFMA-native permuted order  s = lane + 64*ni + 256*r + 1024*mi + 4096*w
// -> every epilogue store is a 256 B full-line write; reduce reads are
// 1 KB-contiguous per 16 threads. Grid (chunks, 2, panels): the two
// m-blocks of a panel-chunk differ by gridDim.x (=8 or 16) in linear id
// -> same XCD under round-robin -> shared-L2 W reads. Heavy panels first.
//   MODE1: nt=2p+2, nc=(p>>2)+1, base=(a+1)*(2a+b), p=4a+b   (32 panels)
//   MODE2: nt=8p+8, nc=p+1,      base=p(p+1)/2               (16 panels)
// ---------------------------------------------------------------------------
template<int MODE>
__global__ __launch_bounds__(512, 2)
void gemm_w(const void* __restrict__ Av, const float* __restrict__ W,
            float* __restrict__ P) {
  constexpr int NPAN = (MODE == 1) ? 32 : 16;
  constexpr int K    = (MODE == 1) ? 4096 : 8192;
  constexpr int N    = (MODE == 1) ? 8192 : 4096;

  __shared__ unsigned short Ws[256 * 64];   // 32 KB
  __shared__ unsigned short Xs[128 * 64];   // 16 KB

  const int p  = NPAN - 1 - (int)blockIdx.z;
  const int mt = blockIdx.y;
  const int c  = blockIdx.x;
  const int nt = (MODE == 1) ? (2 * p + 2) : (8 * p + 8);
  const int i0 = c * 8;
  if (i0 >= nt) return;                     // uniform exit before barriers
  const int i1 = (i0 + 8 < nt) ? (i0 + 8) : nt;
  const int a4 = p >> 2;
  const int base = (MODE == 1) ? ((a4 + 1) * (2 * a4 + (p & 3)))
                               : (p * (p + 1) / 2);
  float* po = P + ((size_t)(base + c) * 2 + mt) * 32768;

  const int tid = threadIdx.x;
  const int lane = tid & 63, w = tid >> 6;
  const int l15 = lane & 15, quad = lane >> 4;
  const int wm = w >> 2, wn = w & 3;
  const int swa = (l15 & 7) << 3;

  // W staging: thread owns row-pair wr0 (within BK), cols wc0..wc0+15
  const int wr0 = (tid >> 4) * 2;
  const int wc0 = (tid & 15) * 16;
  const float* wsrc = W + (size_t)p * 256 + wc0;

  // A staging: thread owns row ar (within BM), k-group ak0..ak0+15
  const int ar = tid >> 2;
  const int ak0 = (tid & 3) * 16;

  float4 wv[8];                             // 2 rows x 16 cols fp32
  float4 av[4];                             // MODE1: 16 fp32
  int4   ab[2];                             // MODE2: 16 bf16

  auto loadW = [&](int kt) {
    const float* r0p = wsrc + (size_t)(kt * 64 + wr0) * N;
#pragma unroll
    for (int j = 0; j < 4; ++j) wv[j] = *(const float4*)(r0p + j * 4);
#pragma unroll
    for (int j = 0; j < 4; ++j) wv[4 + j] = *(const float4*)(r0p + N + j * 4);
  };
  auto storeW = [&](int kt) {
    const int kg = kt * 64 + wr0;
    const float* f = (const float*)wv;
#pragma unroll
    for (int i = 0; i < 16; ++i) {
      const int cc = wc0 + i;
      const int lk = (MODE == 1) ? ((2 * p + (cc >> 7) + 1) * 64)
                                 : ((4 * p + (cc >> 6) + 1) * 128);
      const float v0 = (kg < lk) ? f[i] : 0.f;
      const float v1 = (kg + 1 < lk) ? f[16 + i] : 0.f;
      const int sw = ((cc ^ (cc >> 3)) & 7) << 3;
      *(unsigned*)&Ws[cc * 64 + (wr0 ^ sw)] = b32pair(v0, v1);
    }
  };
  auto loadA = [&](int kt) {
    if constexpr (MODE == 1) {
      const float* ap = (const float*)Av + (size_t)(mt * 128 + ar) * K
                        + kt * 64 + ak0;
#pragma unroll
      for (int j = 0; j < 4; ++j) av[j] = *(const float4*)(ap + j * 4);
    } else {
      const unsigned short* ap = (const unsigned short*)Av
          + (size_t)(mt * 128 + ar) * K + kt * 64 + ak0;
      ab[0] = *(const int4*)ap;
      ab[1] = *(const int4*)(ap + 8);
    }
  };
  auto storeA = [&]() {
    if constexpr (MODE == 1) {
      const float* f = (const float*)av;
      const int sa = (ar & 7) << 3;
#pragma unroll
      for (int j = 0; j < 8; ++j) {
        const int kl = ak0 + 2 * j;
        *(unsigned*)&Xs[ar * 64 + (kl ^ sa)] = b32pair(f[2 * j], f[2 * j + 1]);
      }
    } else {                                 // pre-swizzled: linear copy
      *(int4*)&Xs[ar * 64 + ak0]     = ab[0];
      *(int4*)&Xs[ar * 64 + ak0 + 8] = ab[1];
    }
  };

  f32x4 acc[4][4];
#pragma unroll
  for (int mi = 0; mi < 4; ++mi)
#pragma unroll
    for (int ni = 0; ni < 4; ++ni)
      acc[mi][ni] = (f32x4){0.f, 0.f, 0.f, 0.f};

  loadW(i0);
  loadA(i0);
  for (int it = i0; it < i1; ++it) {
    __syncthreads();                         // prior iter's LDS reads done
    storeW(it);
    storeA();
    if (it + 1 < i1) { loadW(it + 1); loadA(it + 1); }   // prefetch
    __syncthreads();                         // stores visible
#pragma unroll
    for (int kk = 0; kk < 64; kk += 32) {
      bf16x8 af[4], bfr[4];
#pragma unroll
      for (int mi = 0; mi < 4; ++mi)
        af[mi] = *(const bf16x8*)&Xs[(wm * 64 + mi * 16 + l15) * 64
                                     + ((kk + quad * 8) ^ swa)];
#pragma unroll
      for (int ni = 0; ni < 4; ++ni) {
        const int cc = wn * 64 + ni * 16 + l15;
        const int sw = ((cc ^ (cc >> 3)) & 7) << 3;
        bfr[ni] = *(const bf16x8*)&Ws[cc * 64 + ((kk + quad * 8) ^ sw)];
      }
#pragma unroll
      for (int mi = 0; mi < 4; ++mi)
#pragma unroll
        for (int ni = 0; ni < 4; ++ni)
          acc[mi][ni] = __builtin_amdgcn_mfma_f32_16x16x32_bf16(
              af[mi], bfr[ni], acc[mi][ni], 0, 0, 0);
    }
  }

  // epilogue: permuted full-line streaming stores (256 B per wave-instr)
  float* ps = po + w * 4096 + lane;
#pragma unroll
  for (int mi = 0; mi < 4; ++mi)
#pragma unroll
    for (int ni = 0; ni < 4; ++ni)
#pragma unroll
      for (int r = 0; r < 4; ++r)
        ps[ni * 64 + r * 256 + mi * 1024] = acc[mi][ni][r];
}

// Hs[m][n ^ ((m&7)<<3)] = bf16(relu(sum_c P1 + b1)); inverts permuted slots.
__global__ __launch_bounds__(256)
void reduce1(const float* __restrict__ P, const float* __restrict__ b1,
             unsigned short* __restrict__ Hs) {
  const int g = blockIdx.x * 256 + threadIdx.x;   // 2048 blocks
  const int m = g >> 11, n0 = (g & 2047) * 4;
  const int p = n0 >> 8, nl = n0 & 255, ml = m & 127, mb = m >> 7;
  const int a4 = p >> 2;
  const int base = (a4 + 1) * (2 * a4 + (p & 3));
  const int nc = a4 + 1;
  const int lane = ((ml >> 2) & 3) * 16 + (nl & 15);
  const int s = lane + ((nl >> 4) & 3) * 64 + (ml & 3) * 256
              + ((ml >> 4) & 3) * 1024 + (((ml >> 6) << 2) + (nl >> 6)) * 4096;
  const float* ps = P + ((size_t)base * 2 + mb) * 32768 + s;
  f32x4 a = *(const f32x4*)ps;
  for (int ci = 1; ci < nc; ++ci)
    a += *(const f32x4*)(ps + (size_t)ci * 65536);
  a += *(const f32x4*)(b1 + n0);
  union { unsigned short u[4]; int2 v; } t;
#pragma unroll
  for (int j = 0; j < 4; ++j) t.u[j] = f2bf(fmaxf(a[j], 0.f));
  *(int2*)(Hs + (size_t)m * 8192 + (n0 ^ ((m & 7) << 3))) = t.v;
}

// out = sum_c P2 + b2; inverts permuted slots, coalesced f32x4 stores.
__global__ __launch_bounds__(256)
void reduce2(const float* __restrict__ P, const float* __restrict__ b2,
             float* __restrict__ out) {
  const int g = blockIdx.x * 256 + threadIdx.x;   // 1024 blocks
  const int m = g >> 10, n0 = (g & 1023) * 4;
  const int p = n0 >> 8, nl = n0 & 255, ml = m & 127, mb = m >> 7;
  const int base = p * (p + 1) / 2;
  const int nc = p + 1;
  const int lane = ((ml >> 2) & 3) * 16 + (nl & 15);
  const int s = lane + ((nl >> 4) & 3) * 64 + (ml & 3) * 256
              + ((ml >> 4) & 3) * 1024 + (((ml >> 6) << 2) + (nl >> 6)) * 4096;
  const float* ps = P + ((size_t)base * 2 + mb) * 32768 + s;
  f32x4 a = *(const f32x4*)ps;
  for (int ci = 1; ci < nc; ++ci)
    a += *(const f32x4*)(ps + (size_t)ci * 65536);
  a += *(const f32x4*)(b2 + n0);
  *(f32x4*)(out + (size_t)m * 4096 + n0) = a;
}

extern "C" void kernel_launch(void* const* d_in, const int* in_sizes, int n_in,
                              void* d_out, int out_size, void* d_ws, size_t ws_size,
                              hipStream_t stream) {
  const float* x  = (const float*)d_in[0];  // [256,4096] fp32
  const float* W1 = (const float*)d_in[1];  // [4096,8192] fp32
  const float* b1 = (const float*)d_in[2];  // [8192] fp32
  const float* W2 = (const float*)d_in[3];  // [8192,4096] fp32
  const float* b2 = (const float*)d_in[4];  // [4096] fp32
  // dims hardcoded: B=256, S=64, I=64, H=128, O=64

  // workspace (~42 MB): Hs 4 MB | P 37.75 MB (shared by P1/P2)
  char* ws = (char*)d_ws;
  unsigned short* Hs = (unsigned short*)ws;            // 4,194,304 B
  float*          P  = (float*)(ws + 4194304);         // 37,748,736 B
  float* out = (float*)d_out;                          // [256,4096] f32

  // GEMM1: x @ masked-W1 -> P1 (288 slots of 128 KB)
  gemm_w<1><<<dim3(8, 2, 32), 512, 0, stream>>>(x, W1, P);

  // Hs = swizzled bf16 image of relu(sum P1 + b1)
  reduce1<<<dim3(2048), 256, 0, stream>>>(P, b1, Hs);

  // GEMM2: Hs @ masked-W2 -> P2 (272 slots)
  gemm_w<2><<<dim3(16, 2, 16), 512, 0, stream>>>(Hs, W2, P);

  // out = sum P2 + b2
  reduce2<<<dim3(1024), 256, 0, stream>>>(P, b2, out);
}

// Round 6
// 354.690 us; speedup vs baseline: 1.0514x; 1.0514x over previous
//
#include <hip/hip_runtime.h>

typedef short bf16x8 __attribute__((ext_vector_type(8)));
typedef float f32x4 __attribute__((ext_vector_type(4)));

__device__ __forceinline__ unsigned short f2bf(float f) {
  unsigned x = __float_as_uint(f);
  return (unsigned short)((x + 0x7fffu + ((x >> 16) & 1u)) >> 16);  // RNE
}
__device__ __forceinline__ unsigned b32pair(float a, float b) {
  return (unsigned)f2bf(a) | ((unsigned)f2bf(b) << 16);
}

// chunk-slot bases (chunks of 8 BK=64 iters)
__device__ __forceinline__ int cbase1(int p) {   // sum_{q<p} ceil((q+1)/8)
  const int a = p >> 3, b = p & 7;
  return (a + 1) * (4 * a + b);
}
__device__ __forceinline__ int cbase2(int p) {   // sum_{q<p} ceil((q+1)/2)
  const int a = p >> 1, b = p & 1;
  return (a + 1) * (a + b);
}

// ---------------------------------------------------------------------------
// A-images (X, H): bf16 row-major with per-row k-swizzle:
//     img[m*K + (k ^ ((m&7)<<3))]
// -> each lane's MFMA A-fragment is one contiguous 16 B load (L2-resident).
// W: fp32 straight from HBM, staged bf16 into double-buffered LDS:
//     Ws[cc*64 + (k ^ (((cc^(cc>>3))&7)<<3))]
// Split-K partials: per-chunk private 64 KB slots in MFMA-native order
//     s = lane + 64*ni + 256*r + 1024*mi + 4096*w   -> 256 B full-line stores.
// ---------------------------------------------------------------------------

// x [256][4096] f32 -> Ximg [256][4096] bf16 swizzled
__global__ __launch_bounds__(256)
void pack_x(const float* __restrict__ x, unsigned short* __restrict__ img) {
  const int i = (blockIdx.x * 256 + threadIdx.x) * 8;   // 512 blocks
  const int m = i >> 12, k = i & 4095;
  float q[8];
  *(float4*)(q)     = *(const float4*)(x + i);
  *(float4*)(q + 4) = *(const float4*)(x + i + 4);
  union { unsigned short u[8]; int4 v; } t;
#pragma unroll
  for (int j = 0; j < 8; ++j) t.u[j] = f2bf(q[j]);
  *(int4*)(img + (size_t)m * 4096 + (k ^ ((m & 7) << 3))) = t.v;
}

// ---------------------------------------------------------------------------
// GEMM: BM=128, BN=128, BK=64; 256 thr = 4 waves (2m x 2n), 64x64 per wave.
// Single barrier per K-iter (LDS double-buffer for W); ALL global loads for
// iter t+1 (W tile -> regs, A frags -> regs) are issued IMMEDIATELY after the
// barrier so they complete before the span-end consumer / barrier drain.
//   MODE1: panels 64 (x @ W1), nt = p+1  (no masking: panel == mask block)
//   MODE2: panels 32 (H @ W2), nt = 4p+4, left col-half dead on last 2 iters
// Grid (chunks, 2 mt, panels): mt-pair linear ids differ by gridDim.x
// (8 or 16, both ==0 mod 8) -> same XCD -> shared-L2 W reads. Heavy first.
// ---------------------------------------------------------------------------
template<int MODE>
__global__ __launch_bounds__(256, 2)
void gemm_w(const unsigned short* __restrict__ A, const float* __restrict__ W,
            float* __restrict__ P) {
  constexpr int NPAN = (MODE == 1) ? 64 : 32;
  constexpr int AK   = (MODE == 1) ? 4096 : 8192;
  constexpr int N    = (MODE == 1) ? 8192 : 4096;

  __shared__ unsigned short Ws[2][128 * 64];   // 2 x 16 KB

  const int p  = NPAN - 1 - (int)blockIdx.z;   // heavy panels first
  const int mt = blockIdx.y;
  const int c  = blockIdx.x;
  const int nt = (MODE == 1) ? (p + 1) : (4 * p + 4);
  const int i0 = c * 8;
  if (i0 >= nt) return;                        // uniform exit before barriers
  const int i1 = (i0 + 8 < nt) ? (i0 + 8) : nt;
  const int bs = (MODE == 1) ? cbase1(p) : cbase2(p);
  float* po = P + ((size_t)(bs + c) * 2 + mt) * 16384;

  const int tid = threadIdx.x, lane = tid & 63, w = tid >> 6;
  const int l15 = lane & 15, quad = lane >> 4;
  const int wm = w >> 1, wn = w & 1;

  // W staging: thread owns k-rows {wr0, wr0+1}, cols wc0..wc0+15
  const int wr0 = (tid >> 3) * 2;
  const int wc0 = (tid & 7) * 16;
  const float* wsrc = W + (size_t)p * 128 + wc0;
  const int lk = (MODE == 2) ? (2 * p + 1 + (wc0 >> 6)) * 128 : 0x7fffffff;

  // per-lane A-fragment offsets (swizzle confined to low 6 bits)
  int aoff[4][2];
#pragma unroll
  for (int mi = 0; mi < 4; ++mi) {
    const int m = mt * 128 + wm * 64 + mi * 16 + l15;
#pragma unroll
    for (int h = 0; h < 2; ++h)
      aoff[mi][h] = m * AK + ((h * 32 + quad * 8) ^ ((m & 7) << 3));
  }

  float4 wv[8];                                // next W tile (2 rows x 16 f32)
  auto loadW = [&](int kt) {
    const float* r0 = wsrc + (size_t)(kt * 64 + wr0) * N;
#pragma unroll
    for (int j = 0; j < 4; ++j) wv[j] = *(const float4*)(r0 + j * 4);
#pragma unroll
    for (int j = 0; j < 4; ++j) wv[4 + j] = *(const float4*)(r0 + N + j * 4);
  };
  auto storeW = [&](int buf, int kt) {
    const float* f = (const float*)wv;
    const int kg = kt * 64 + wr0;
#pragma unroll
    for (int i = 0; i < 16; ++i) {
      const int cc = wc0 + i;
      float v0 = f[i], v1 = f[16 + i];
      if (MODE == 2) { v0 = (kg < lk) ? v0 : 0.f; v1 = (kg + 1 < lk) ? v1 : 0.f; }
      const int sw = ((cc ^ (cc >> 3)) & 7) << 3;
      *(unsigned*)&Ws[buf][cc * 64 + (wr0 ^ sw)] = b32pair(v0, v1);
    }
  };
  auto loadA = [&](bf16x8 (&af)[4][2], int kt) {
    const unsigned short* at = A + (size_t)kt * 64;
#pragma unroll
    for (int mi = 0; mi < 4; ++mi)
#pragma unroll
      for (int h = 0; h < 2; ++h)
        af[mi][h] = *(const bf16x8*)(at + aoff[mi][h]);
  };

  f32x4 acc[4][4];
#pragma unroll
  for (int mi = 0; mi < 4; ++mi)
#pragma unroll
    for (int ni = 0; ni < 4; ++ni)
      acc[mi][ni] = (f32x4){0.f, 0.f, 0.f, 0.f};

  bf16x8 afA[4][2], afB[4][2];

  // prologue: stage tile i0, load its A frags
  loadW(i0);
  loadA(afA, i0);
  storeW(0, i0);                               // waits wv only (vmcnt(8))
  __syncthreads();                             // buf0 visible (one-time drain)

  int cur = 0;
  auto ITER = [&](bf16x8 (&caf)[4][2], bf16x8 (&naf)[4][2], int t) {
    const bool pre = (t + 1 < i1);
    if (pre) { loadW(t + 1); loadA(naf, t + 1); }  // issue at span START
    const unsigned short* Wb = &Ws[cur][0];
#pragma unroll
    for (int h = 0; h < 2; ++h) {
      const int kk = h * 32;
      bf16x8 bfr[4];
#pragma unroll
      for (int ni = 0; ni < 4; ++ni) {
        const int cc = wn * 64 + ni * 16 + l15;
        const int sw = ((cc ^ (cc >> 3)) & 7) << 3;
        bfr[ni] = *(const bf16x8*)&Wb[cc * 64 + ((kk + quad * 8) ^ sw)];
      }
#pragma unroll
      for (int mi = 0; mi < 4; ++mi)
#pragma unroll
        for (int ni = 0; ni < 4; ++ni)
          acc[mi][ni] = __builtin_amdgcn_mfma_f32_16x16x32_bf16(
              caf[mi][h], bfr[ni], acc[mi][ni], 0, 0, 0);
    }
    if (pre) {
      storeW(cur ^ 1, t + 1);                  // waits wv; naf stays in flight
      __syncthreads();                         // drain is cheap: loads ~done
    }
    cur ^= 1;
  };

  int t = i0;
  while (true) {
    ITER(afA, afB, t); if (++t >= i1) break;
    ITER(afB, afA, t); if (++t >= i1) break;
  }

  // epilogue: permuted full-line streaming stores (256 B per wave-instr)
  float* ps = po + w * 4096 + lane;
#pragma unroll
  for (int mi = 0; mi < 4; ++mi)
#pragma unroll
    for (int ni = 0; ni < 4; ++ni)
#pragma unroll
      for (int r = 0; r < 4; ++r)
        ps[ni * 64 + r * 256 + mi * 1024] = acc[mi][ni][r];
}

// Hs = swizzled bf16 image of relu(sum_c P1 + b1); inverts permuted slots.
__global__ __launch_bounds__(256)
void reduce1(const float* __restrict__ P, const float* __restrict__ b1,
             unsigned short* __restrict__ Hs) {
  const int g = blockIdx.x * 256 + threadIdx.x;   // 2048 blocks
  const int m = g >> 11, n0 = (g & 2047) * 4;
  const int p = n0 >> 7, nl = n0 & 127, mb = m >> 7, ml = m & 127;
  const int s = (((ml >> 2) & 3) * 16 + (nl & 15)) + ((nl >> 4) & 3) * 64
              + (ml & 3) * 256 + ((ml >> 4) & 3) * 1024
              + (((ml >> 6) << 1) + (nl >> 6)) * 4096;
  const int nc = (p + 8) >> 3;
  const float* ps = P + ((size_t)cbase1(p) * 2 + mb) * 16384 + s;
  f32x4 a = *(const f32x4*)ps;
  for (int ci = 1; ci < nc; ++ci)
    a += *(const f32x4*)(ps + (size_t)ci * 32768);
  a += *(const f32x4*)(b1 + n0);
  union { unsigned short u[4]; int2 v; } t;
#pragma unroll
  for (int j = 0; j < 4; ++j) t.u[j] = f2bf(fmaxf(a[j], 0.f));
  *(int2*)(Hs + (size_t)m * 8192 + (n0 ^ ((m & 7) << 3))) = t.v;
}

// out = sum_c P2 + b2; inverts permuted slots, coalesced f32x4 stores.
__global__ __launch_bounds__(256)
void reduce2(const float* __restrict__ P, const float* __restrict__ b2,
             float* __restrict__ out) {
  const int g = blockIdx.x * 256 + threadIdx.x;   // 1024 blocks
  const int m = g >> 10, n0 = (g & 1023) * 4;
  const int p = n0 >> 7, nl = n0 & 127, mb = m >> 7, ml = m & 127;
  const int s = (((ml >> 2) & 3) * 16 + (nl & 15)) + ((nl >> 4) & 3) * 64
              + (ml & 3) * 256 + ((ml >> 4) & 3) * 1024
              + (((ml >> 6) << 1) + (nl >> 6)) * 4096;
  const int nc = (p + 2) >> 1;
  const float* ps = P + ((size_t)cbase2(p) * 2 + mb) * 16384 + s;
  f32x4 a = *(const f32x4*)ps;
  for (int ci = 1; ci < nc; ++ci)
    a += *(const f32x4*)(ps + (size_t)ci * 32768);
  a += *(const f32x4*)(b2 + n0);
  *(f32x4*)(out + (size_t)m * 4096 + n0) = a;
}

extern "C" void kernel_launch(void* const* d_in, const int* in_sizes, int n_in,
                              void* d_out, int out_size, void* d_ws, size_t ws_size,
                              hipStream_t stream) {
  const float* x  = (const float*)d_in[0];  // [256,4096] fp32
  const float* W1 = (const float*)d_in[1];  // [4096,8192] fp32
  const float* b1 = (const float*)d_in[2];  // [8192] fp32
  const float* W2 = (const float*)d_in[3];  // [8192,4096] fp32
  const float* b2 = (const float*)d_in[4];  // [4096] fp32
  // dims hardcoded: B=256, S=64, I=64, H=128, O=64

  // workspace (~44 MB): Ximg 2 MB | Hs 4 MB | P 37.75 MB (shared P1/P2)
  char* ws = (char*)d_ws;
  unsigned short* Ximg = (unsigned short*)ws;           // 2,097,152 B
  unsigned short* Hs   = (unsigned short*)(ws + 2097152);  // 4,194,304 B
  float*          P    = (float*)(ws + 6291456);        // 37,748,736 B
  float* out = (float*)d_out;                           // [256,4096] f32

  pack_x<<<dim3(512), 256, 0, stream>>>(x, Ximg);

  // GEMM1: Ximg @ W1 -> P1 (576 slots of 64 KB).  nt = p+1, 64 panels.
  gemm_w<1><<<dim3(8, 2, 64), 256, 0, stream>>>(Ximg, W1, P);

  // Hs = swizzled bf16 image of relu(sum P1 + b1)
  reduce1<<<dim3(2048), 256, 0, stream>>>(P, b1, Hs);

  // GEMM2: Hs @ W2 -> P2 (544 slots).  nt = 4p+4, 32 panels.
  gemm_w<2><<<dim3(16, 2, 32), 256, 0, stream>>>(Hs, W2, P);

  // out = sum P2 + b2
  reduce2<<<dim3(1024), 256, 0, stream>>>(P, b2, out);
}

// Round 9
// 332.435 us; speedup vs baseline: 1.1217x; 1.0669x over previous
//
#include <hip/hip_runtime.h>

typedef short bf16x8 __attribute__((ext_vector_type(8)));
typedef float f32x4 __attribute__((ext_vector_type(4)));

__device__ __forceinline__ unsigned short f2bf(float f) {
  unsigned x = __float_as_uint(f);
  return (unsigned short)((x + 0x7fffu + ((x >> 16) & 1u)) >> 16);  // RNE
}
__device__ __forceinline__ unsigned b32pair(float a, float b) {
  return (unsigned)f2bf(a) | ((unsigned)f2bf(b) << 16);
}

// chunk-slot bases (chunks of 8 BK=64 iters, BN=64 panels)
// gemm1: nt(p) = (p>>1)+1, nc = ceil(nt/8);  base1 = sum_{q<p} nc(q)
__device__ __forceinline__ int cbase1(int p) {
  const int a = p >> 1, b = p & 1;
  const int u = a >> 3, v = a & 7;                  // S(a)=sum_{j<a}ceil((j+1)/8)
  return 2 * (4 * u * (u - 1) + v * u + a) + b * ((a + 8) >> 3);
}
// gemm2: nt(p) = 2(p+1), nc = (p>>2)+1;  base2 = sum_{q<p} nc(q)
__device__ __forceinline__ int cbase2(int p) {
  const int w = p >> 2, r = p & 3;
  return 2 * w * (w - 1) + r * w + p;
}

// ---------------------------------------------------------------------------
// A-images (X, H): bf16 row-major, per-row k-swizzle  img[m*K + (k^((m&7)<<3))]
// -> each lane's MFMA A-fragment is one contiguous 16 B load (L2-resident).
// W: fp32 straight from HBM (read EXACTLY once: BM=256 covers all of M),
// staged bf16 into double-buffered LDS: Ws[cc*64 + (k ^ (((cc^(cc>>3))&7)<<3))]
// BN=64 == mask col-block granularity -> masking is purely nt, no zeroing.
// Split-K partials: per-chunk 64 KB slots in MFMA-native permuted order
//     s = lane + 64*ni + 256*r + 1024*mi + 4096*w   (w = m>>6: wave's m-quad)
// -> every epilogue store is a 256 B full-line write.
// (R9: same algorithm as R7/R8; main loop restructured to a bounded for-loop
//  after two container-level failures — semantics unchanged.)
// ---------------------------------------------------------------------------

// x [256][4096] f32 -> Ximg [256][4096] bf16 swizzled
__global__ __launch_bounds__(256)
void pack_x(const float* __restrict__ x, unsigned short* __restrict__ img) {
  const int i = (blockIdx.x * 256 + threadIdx.x) * 8;   // 512 blocks
  const int m = i >> 12, k = i & 4095;
  float q[8];
  *(float4*)(q)     = *(const float4*)(x + i);
  *(float4*)(q + 4) = *(const float4*)(x + i + 4);
  union { unsigned short u[8]; int4 v; } t;
#pragma unroll
  for (int j = 0; j < 8; ++j) t.u[j] = f2bf(q[j]);
  *(int4*)(img + (size_t)m * 4096 + (k ^ ((m & 7) << 3))) = t.v;
}

// ---------------------------------------------------------------------------
// GEMM: BM=256 (all M), BN=64, BK=64; 256 thr = 4 waves stacked in m, each
// wave owns m in [64w, 64w+64) and the full 64 N-cols (acc 4x4 frags).
// Single barrier per K-iter; all global loads for iter t+1 issued at span
// start so latency hides under MFMA + LDS reads.
//   MODE1: 128 panels (x @ W1),  nt = (p>>1)+1
//   MODE2:  64 panels (Hs @ W2), nt = 2(p+1)
// Heavy panels first; empty chunks exit before any barrier.
// ---------------------------------------------------------------------------
template<int MODE>
__global__ __launch_bounds__(256, 2)
void gemm_w(const unsigned short* __restrict__ A, const float* __restrict__ W,
            float* __restrict__ P) {
  constexpr int NPAN = (MODE == 1) ? 128 : 64;
  constexpr int AK   = (MODE == 1) ? 4096 : 8192;
  constexpr int N    = (MODE == 1) ? 8192 : 4096;

  __shared__ unsigned short Ws[2][64 * 64];    // 2 x 8 KB

  const int p = NPAN - 1 - (int)blockIdx.z;    // heavy panels first
  const int c = blockIdx.x;
  const int nt = (MODE == 1) ? ((p >> 1) + 1) : (2 * p + 2);
  const int i0 = c * 8;
  if (i0 >= nt) return;                        // uniform exit before barriers
  const int i1 = (i0 + 8 < nt) ? (i0 + 8) : nt;
  const int bs = (MODE == 1) ? cbase1(p) : cbase2(p);
  float* po = P + (size_t)(bs + c) * 16384;

  const int tid = threadIdx.x, lane = tid & 63, w = tid >> 6;
  const int l15 = lane & 15, quad = lane >> 4;

  // W staging: thread owns k-rows {wr0, wr0+1}, cols wc0..wc0+7
  const int wr0 = (tid >> 3) * 2;
  const int wc0 = (tid & 7) * 8;
  const float* wsrc = W + (size_t)p * 64 + wc0;

  // per-lane A-fragment offsets (swizzle confined to low 6 bits of k)
  int aoff[4][2];
#pragma unroll
  for (int mi = 0; mi < 4; ++mi) {
    const int m = w * 64 + mi * 16 + l15;
#pragma unroll
    for (int h = 0; h < 2; ++h)
      aoff[mi][h] = m * AK + ((h * 32 + quad * 8) ^ ((m & 7) << 3));
  }

  float4 wv[4];                                // 2 k-rows x 8 cols fp32
  auto loadW = [&](int kt) {
    const float* r0 = wsrc + (size_t)(kt * 64 + wr0) * N;
    wv[0] = *(const float4*)(r0);
    wv[1] = *(const float4*)(r0 + 4);
    wv[2] = *(const float4*)(r0 + N);
    wv[3] = *(const float4*)(r0 + N + 4);
  };
  auto storeW = [&](int buf) {
    const float* f = (const float*)wv;
#pragma unroll
    for (int i = 0; i < 8; ++i) {
      const int cc = wc0 + i;
      const int sw = ((cc ^ (cc >> 3)) & 7) << 3;
      *(unsigned*)&Ws[buf][cc * 64 + (wr0 ^ sw)] = b32pair(f[i], f[8 + i]);
    }
  };
  auto loadA = [&](bf16x8 (&af)[4][2], int kt) {
    const unsigned short* at = A + (size_t)kt * 64;
#pragma unroll
    for (int mi = 0; mi < 4; ++mi)
#pragma unroll
      for (int h = 0; h < 2; ++h)
        af[mi][h] = *(const bf16x8*)(at + aoff[mi][h]);
  };

  f32x4 acc[4][4];
#pragma unroll
  for (int mi = 0; mi < 4; ++mi)
#pragma unroll
    for (int ni = 0; ni < 4; ++ni)
      acc[mi][ni] = (f32x4){0.f, 0.f, 0.f, 0.f};

  bf16x8 afA[4][2], afB[4][2];

  // prologue: stage tile i0, load its A frags
  loadW(i0);
  loadA(afA, i0);
  storeW(0);                                   // waits on wv only
  __syncthreads();                             // buf0 visible

  // one K-iter: consume caf + Ws[buf]; prefetch t+1 into naf + Ws[buf^1]
  auto ITER = [&](bf16x8 (&caf)[4][2], bf16x8 (&naf)[4][2], int t, int buf) {
    const bool pre = (t + 1 < i1);             // uniform
    if (pre) { loadW(t + 1); loadA(naf, t + 1); }   // issue at span START
    const unsigned short* Wb = &Ws[buf][0];
#pragma unroll
    for (int h = 0; h < 2; ++h) {
      const int kk = h * 32;
      bf16x8 bfr[4];
#pragma unroll
      for (int ni = 0; ni < 4; ++ni) {
        const int cc = ni * 16 + l15;
        const int sw = ((cc ^ (cc >> 3)) & 7) << 3;
        bfr[ni] = *(const bf16x8*)&Wb[cc * 64 + ((kk + quad * 8) ^ sw)];
      }
#pragma unroll
      for (int mi = 0; mi < 4; ++mi)
#pragma unroll
        for (int ni = 0; ni < 4; ++ni)
          acc[mi][ni] = __builtin_amdgcn_mfma_f32_16x16x32_bf16(
              caf[mi][h], bfr[ni], acc[mi][ni], 0, 0, 0);
    }
    if (pre) {
      storeW(buf ^ 1);                         // waits wv; naf stays in flight
      __syncthreads();
    }
  };

  // bounded pair-loop; frag/buffer indices static in each body (rule #20)
  for (int t = i0; t < i1; t += 2) {
    ITER(afA, afB, t, 0);
    if (t + 1 < i1) ITER(afB, afA, t + 1, 1);
  }

  // epilogue: permuted full-line streaming stores (256 B per wave-instr)
  float* ps = po + w * 4096 + lane;
#pragma unroll
  for (int mi = 0; mi < 4; ++mi)
#pragma unroll
    for (int ni = 0; ni < 4; ++ni)
#pragma unroll
      for (int r = 0; r < 4; ++r)
        ps[ni * 64 + r * 256 + mi * 1024] = acc[mi][ni][r];
}

// Hs = swizzled bf16 image of relu(sum_c P1 + b1); inverts permuted slots.
__global__ __launch_bounds__(256)
void reduce1(const float* __restrict__ P, const float* __restrict__ b1,
             unsigned short* __restrict__ Hs) {
  const int g = blockIdx.x * 256 + threadIdx.x;   // 2048 blocks
  const int m = g >> 11, n0 = (g & 2047) * 4;
  const int p = n0 >> 6, nl = n0 & 63;
  const int s = ((m >> 2) & 3) * 16 + (nl & 15) + (nl >> 4) * 64
              + (m & 3) * 256 + ((m >> 4) & 3) * 1024 + (m >> 6) * 4096;
  const int nc = ((p >> 1) + 8) >> 3;
  const float* ps = P + (size_t)cbase1(p) * 16384 + s;
  f32x4 a = *(const f32x4*)ps;
  for (int ci = 1; ci < nc; ++ci)
    a += *(const f32x4*)(ps + (size_t)ci * 16384);
  a += *(const f32x4*)(b1 + n0);
  union { unsigned short u[4]; int2 v; } t;
#pragma unroll
  for (int j = 0; j < 4; ++j) t.u[j] = f2bf(fmaxf(a[j], 0.f));
  *(int2*)(Hs + (size_t)m * 8192 + (n0 ^ ((m & 7) << 3))) = t.v;
}

// out = sum_c P2 + b2; inverts permuted slots, coalesced f32x4 stores.
__global__ __launch_bounds__(256)
void reduce2(const float* __restrict__ P, const float* __restrict__ b2,
             float* __restrict__ out) {
  const int g = blockIdx.x * 256 + threadIdx.x;   // 1024 blocks
  const int m = g >> 10, n0 = (g & 1023) * 4;
  const int p = n0 >> 6, nl = n0 & 63;
  const int s = ((m >> 2) & 3) * 16 + (nl & 15) + (nl >> 4) * 64
              + (m & 3) * 256 + ((m >> 4) & 3) * 1024 + (m >> 6) * 4096;
  const int nc = (p >> 2) + 1;
  const float* ps = P + (size_t)cbase2(p) * 16384 + s;
  f32x4 a = *(const f32x4*)ps;
  for (int ci = 1; ci < nc; ++ci)
    a += *(const f32x4*)(ps + (size_t)ci * 16384);
  a += *(const f32x4*)(b2 + n0);
  *(f32x4*)(out + (size_t)m * 4096 + n0) = a;
}

extern "C" void kernel_launch(void* const* d_in, const int* in_sizes, int n_in,
                              void* d_out, int out_size, void* d_ws, size_t ws_size,
                              hipStream_t stream) {
  const float* x  = (const float*)d_in[0];  // [256,4096] fp32
  const float* W1 = (const float*)d_in[1];  // [4096,8192] fp32
  const float* b1 = (const float*)d_in[2];  // [8192] fp32
  const float* W2 = (const float*)d_in[3];  // [8192,4096] fp32
  const float* b2 = (const float*)d_in[4];  // [4096] fp32
  // dims hardcoded: B=256, S=64, I=64, H=128, O=64

  // workspace (~44 MB): Ximg 2 MB | Hs 4 MB | P 36.9 MB (shared P1/P2)
  char* ws = (char*)d_ws;
  unsigned short* Ximg = (unsigned short*)ws;              // 2,097,152 B
  unsigned short* Hs   = (unsigned short*)(ws + 2097152);  // 4,194,304 B
  float*          P    = (float*)(ws + 6291456);           // 37,748,736 B
  float* out = (float*)d_out;                              // [256,4096] f32

  pack_x<<<dim3(512), 256, 0, stream>>>(x, Ximg);

  // GEMM1: Ximg @ W1 -> P1 (576 slots of 64 KB).  nt = (p>>1)+1, 128 panels.
  gemm_w<1><<<dim3(8, 1, 128), 256, 0, stream>>>(Ximg, W1, P);

  // Hs = swizzled bf16 image of relu(sum P1 + b1)
  reduce1<<<dim3(2048), 256, 0, stream>>>(P, b1, Hs);

  // GEMM2: Hs @ W2 -> P2 (544 slots).  nt = 2(p+1), 64 panels.
  gemm_w<2><<<dim3(16, 1, 64), 256, 0, stream>>>(Hs, W2, P);

  // out = sum P2 + b2
  reduce2<<<dim3(1024), 256, 0, stream>>>(P, b2, out);
}